// Round 6
// baseline (253.466 us; speedup 1.0000x reference)
//
#include <hip/hip_runtime.h>
#include <hip/hip_bf16.h>

#define N_NODES 4096
#define C_DIM   512
#define L_DIM   64
#define SPLITS  8
#define KCHUNK  (N_NODES / SPLITS)   // 512

typedef unsigned short u16;
using bf16x8 = __attribute__((ext_vector_type(8))) __bf16;
using u16x8  = __attribute__((ext_vector_type(8))) unsigned short;
using f32x4  = __attribute__((ext_vector_type(4))) float;

__device__ __forceinline__ float b2f(u16 u) {
    union { unsigned int i; float f; } v; v.i = ((unsigned int)u) << 16; return v.f;
}
__device__ __forceinline__ u16 f2b(float f) {
    unsigned int u = __float_as_uint(f);
    u += 0x7fff + ((u >> 16) & 1);   // round-to-nearest-even
    return (u16)(u >> 16);
}

__device__ __forceinline__ void gload16(const u16* g, u16* l) {
    __builtin_amdgcn_global_load_lds((const __attribute__((address_space(1))) void*)g,
                                     (__attribute__((address_space(3))) void*)l,
                                     16, 0, 0);
}

// mode: 0 = inputs bf16, 1 = inputs f32. adj ~ U[0,1): bf16 u16 <= 0x3F80;
// f32 low-half u16s are random mantissa (>=0x8000 w.p. 1/2). P[err] = 2^-32.
__device__ __forceinline__ int detect_mode_inl(const u16* __restrict__ adj) {
    int m = 0;
#pragma unroll
    for (int i = 0; i < 64; ++i) m |= (adj[i] >= 0x8000) ? 1 : 0;
    return m;
}

// ---- workspace byte offsets ----
#define OFF_DT    64
#define OFF_BIAS  1024
#define OFF_WP    4096
#define OFF_BP    135168
#define OFF_WP1   135424
#define OFF_BP1   266496
#define OFF_WP2   268544
#define OFF_BP2   270592
#define OFF_Q     271360
#define OFF_S     287744
#define OFF_DV    304128
#define OFF_T     1048576
#define OFF_TST   9437184
#define OFF_WFT   13631488
#define OFF_XB    14155776
#define OFF_ADJB  18350080   // 32 MB; in bf16 mode doubles as f32 Pacc (8 MB)

__device__ __forceinline__ float ldin(const void* p, int i, int mode) {
    if (mode) return ((const float*)p)[i];
    return b2f(((const u16*)p)[i]);
}

// ================= K1: convert params | x->bf16 | adj rowsum+bf16 | Wf^T =================
// blocks: [0,263) convert, [263,2311) prep_x, [2311,3335) prep_adj, [3335,3591) trans_Wf
__global__ __launch_bounds__(256) void k1_prep(const void* __restrict__ adj, const void* __restrict__ x,
        const void* Wp, const void* bp, const void* Wp1, const void* bp1,
        const void* Wp2, const void* bp2, const void* Wf, const void* bfc, const void* dt,
        float* __restrict__ Wp_f, float* __restrict__ bp_f, float* __restrict__ Wp1_f,
        float* __restrict__ bp1_f, float* __restrict__ Wp2_f, float* __restrict__ bp2_f,
        float* __restrict__ bias_f, float* __restrict__ dt_f,
        u16* __restrict__ adjb, float* __restrict__ q, u16* __restrict__ xb,
        u16* __restrict__ WfT) {
    __shared__ float tile[32][33];
    int bid = blockIdx.x, tid = threadIdx.x;
    int mode = detect_mode_inl((const u16*)adj);
    if (bid < 263) {
        int idx = bid * 256 + tid;
        if (idx < 32768)        Wp_f[idx]          = ldin(Wp,  idx, mode);
        else if (idx < 32832)   bp_f[idx - 32768]  = ldin(bp,  idx - 32768, mode);
        else if (idx < 65600)   Wp1_f[idx - 32832] = ldin(Wp1, idx - 32832, mode);
        else if (idx < 66112)   bp1_f[idx - 65600] = ldin(bp1, idx - 65600, mode);
        else if (idx < 66624)   Wp2_f[idx - 66112] = ldin(Wp2, idx - 66112, mode);
        else if (idx == 66624)  bp2_f[0]           = ldin(bp2, 0, mode);
        else if (idx < 67137)   bias_f[idx - 66625] = ldin(bfc, idx - 66625, mode);
        else if (idx == 67137)  dt_f[0]            = ldin(dt, 0, mode);
    } else if (bid < 2311) {
        if (mode == 0) return;
        int idx = (bid - 263) * 256 + tid;
        float4 v = ((const float4*)x)[idx];
        ushort4 o; o.x = f2b(v.x); o.y = f2b(v.y); o.z = f2b(v.z); o.w = f2b(v.w);
        ((ushort4*)xb)[idx] = o;
    } else if (bid < 3335) {
        int wave = tid >> 6, lane = tid & 63;
        int row = (bid - 2311) * 4 + wave;
        float acc = 0.f;
        if (mode) {
            const float4* rp = (const float4*)((const float*)adj + (size_t)row * N_NODES);
            ushort4* wp = (ushort4*)(adjb + (size_t)row * N_NODES);
#pragma unroll
            for (int it = 0; it < 16; ++it) {
                float4 v = rp[it * 64 + lane];
                acc += v.x + v.y + v.z + v.w;
                ushort4 o; o.x = f2b(v.x); o.y = f2b(v.y); o.z = f2b(v.z); o.w = f2b(v.w);
                wp[it * 64 + lane] = o;
            }
        } else {
            const u16x8* rp = (const u16x8*)((const u16*)adj + (size_t)row * N_NODES);
#pragma unroll
            for (int it = 0; it < 8; ++it) {
                u16x8 v = rp[it * 64 + lane];
#pragma unroll
                for (int e = 0; e < 8; ++e) acc += b2f(v[e]);
            }
        }
#pragma unroll
        for (int off = 32; off > 0; off >>= 1) acc += __shfl_down(acc, off);
        if (lane == 0) q[row] = acc;
    } else {
        int g = bid - 3335;
        int tx = tid & 31, ty = tid >> 5;
        int x0 = (g & 15) * 32, y0 = (g >> 4) * 32;
        if (mode) {
            const float* src = (const float*)Wf;
#pragma unroll
            for (int r = ty; r < 32; r += 8) tile[r][tx] = src[(size_t)(y0 + r) * C_DIM + x0 + tx];
        } else {
            const u16* src = (const u16*)Wf;
#pragma unroll
            for (int r = ty; r < 32; r += 8) tile[r][tx] = b2f(src[(size_t)(y0 + r) * C_DIM + x0 + tx]);
        }
        __syncthreads();
#pragma unroll
        for (int r = ty; r < 32; r += 8)
            WfT[(size_t)(x0 + r) * C_DIM + y0 + tx] = f2b(tile[tx][r]);
    }
}

// ================= K2: pi-MLP (blocks [0,512)) | gemm1 relu(x@Wf+b) (blocks [512,1024)) ====
// gemm1 epilogue also writes tgt = (1-dt)*T (the accumulator init for k4's atomics)
__global__ __launch_bounds__(256) void k2_pi_gemm1(const void* __restrict__ xraw,
        const u16* __restrict__ adjdet, const u16* __restrict__ xb, const u16* __restrict__ WfT,
        const float* __restrict__ Wp_f,  const float* __restrict__ bp_f,
        const float* __restrict__ Wp1_f, const float* __restrict__ bp1_f,
        const float* __restrict__ Wp2_f, const float* __restrict__ bp2_f,
        const float* __restrict__ bias_f, const float* __restrict__ dt_f,
        const float* __restrict__ q, float* __restrict__ s, float* __restrict__ T,
        void* __restrict__ out, float* __restrict__ Pacc) {
    __shared__ __align__(16) char smem[18560];
    int bid = blockIdx.x, tid = threadIdx.x;
    int mode = detect_mode_inl(adjdet);
    if (bid < 512) {
        float (*sx)[C_DIM] = (float(*)[C_DIM])smem;
        float (*sz)[L_DIM] = (float(*)[L_DIM])(smem + 16384);
        float (*red)[8]    = (float(*)[8])(smem + 18432);
        int i0 = bid * 8;
        if (mode) {
            const float4* xp = (const float4*)((const float*)xraw + (size_t)i0 * C_DIM);
            float4* sxf = (float4*)&sx[0][0];
#pragma unroll
            for (int r = 0; r < 4; ++r) sxf[tid + 256 * r] = xp[tid + 256 * r];
        } else {
            const u16x8* xp = (const u16x8*)((const u16*)xraw + (size_t)i0 * C_DIM);
#pragma unroll
            for (int r = 0; r < 2; ++r) {
                u16x8 v = xp[tid + 256 * r];
                float* dstf = &sx[0][0] + (size_t)(tid + 256 * r) * 8;
#pragma unroll
                for (int e = 0; e < 8; ++e) dstf[e] = b2f(v[e]);
            }
        }
        __syncthreads();
        int j = tid & 63, n0 = tid >> 6;
        float a0 = 0.f, a1 = 0.f;
#pragma unroll 4
        for (int k = 0; k < C_DIM; ++k) {
            float w = Wp_f[k * L_DIM + j];
            a0 += sx[n0][k] * w;
            a1 += sx[n0 + 4][k] * w;
        }
        sz[n0][j] = a0 + bp_f[j];
        sz[n0 + 4][j] = a1 + bp_f[j];
        __syncthreads();
        int m0 = tid, m1 = tid + 256;
        float b0 = bp1_f[m0], b1 = bp1_f[m1];
        float h0[8], h1[8];
#pragma unroll
        for (int n = 0; n < 8; ++n) { h0[n] = b0; h1[n] = b1; }
#pragma unroll 8
        for (int jj = 0; jj < L_DIM; ++jj) {
            float w0 = Wp1_f[jj * C_DIM + m0];
            float w1 = Wp1_f[jj * C_DIM + m1];
#pragma unroll
            for (int n = 0; n < 8; ++n) {
                float z = sz[n][jj];
                h0[n] += z * w0;
                h1[n] += z * w1;
            }
        }
        float w2a = Wp2_f[m0], w2b = Wp2_f[m1];
        float p[8];
#pragma unroll
        for (int n = 0; n < 8; ++n)
            p[n] = fmaxf(h0[n], 0.f) * w2a + fmaxf(h1[n], 0.f) * w2b;
#pragma unroll
        for (int off = 32; off > 0; off >>= 1)
#pragma unroll
            for (int n = 0; n < 8; ++n) p[n] += __shfl_down(p[n], off);
        int lane = tid & 63, wave = tid >> 6;
        if (lane == 0) {
#pragma unroll
            for (int n = 0; n < 8; ++n) red[wave][n] = p[n];
        }
        __syncthreads();
        if (tid < 8) {
            float tot = red[0][tid] + red[1][tid] + red[2][tid] + red[3][tid] + bp2_f[0];
            float pi = 1.f / (1.f + expf(-tot));
            s[i0 + tid] = pi / q[i0 + tid];
        }
    } else {
        // gemm1: 64x64 tile, A = x (bf16), B = WfT, K = 512; T = relu(acc + bias)
        u16* lA = (u16*)smem;
        u16* lB = (u16*)(smem + 4096);
        const u16* A = mode ? xb : (const u16*)xraw;
        float* tgt = mode ? (float*)out : Pacc;
        int g = bid - 512;
        int lane = tid & 63, wave = tid >> 6;
        int bm = (g & 63) * 64, bn = (g >> 6) * 64;
        int quad = lane >> 4, l15 = lane & 15;
        int wm = wave * 16;
        const u16* Ap = A + (size_t)(bm + (tid >> 2)) * C_DIM + (tid & 3) * 8;
        const u16* Bp = WfT + (size_t)(bn + (tid >> 2)) * C_DIM + (tid & 3) * 8;
        u16* la = lA + tid * 8;
        u16* lb = lB + tid * 8;
        f32x4 acc[4];
#pragma unroll
        for (int nt = 0; nt < 4; ++nt) acc[nt] = (f32x4){0.f, 0.f, 0.f, 0.f};
        for (int k0 = 0; k0 < C_DIM; k0 += 32) {
            gload16(Ap + k0, la);
            gload16(Bp + k0, lb);
            __syncthreads();
            bf16x8 af = *(const bf16x8*)&lA[(wm + l15) * 32 + quad * 8];
            bf16x8 bfv[4];
#pragma unroll
            for (int nt = 0; nt < 4; ++nt) bfv[nt] = *(const bf16x8*)&lB[(nt * 16 + l15) * 32 + quad * 8];
#pragma unroll
            for (int nt = 0; nt < 4; ++nt)
                acc[nt] = __builtin_amdgcn_mfma_f32_16x16x32_bf16(af, bfv[nt], acc[nt], 0, 0, 0);
            __syncthreads();
        }
        float c0 = 1.f - dt_f[0];
#pragma unroll
        for (int nt = 0; nt < 4; ++nt) {
            int col = bn + nt * 16 + l15;
            float bv = bias_f[col];
#pragma unroll
            for (int r = 0; r < 4; ++r) {
                int row = bm + wm + quad * 4 + r;
                float t = fmaxf(acc[nt][r] + bv, 0.f);
                T[(size_t)row * C_DIM + col] = t;
                tgt[(size_t)row * C_DIM + col] = c0 * t;
            }
        }
    }
}

// ================= K3: dvec [0,1024) | trans_scale [1024,3072) =================
__global__ __launch_bounds__(256) void k3_mid(const void* __restrict__ adjraw,
        const u16* __restrict__ adjb, const float* __restrict__ s,
        const float* __restrict__ T,
        float* __restrict__ dv, u16* __restrict__ TsT) {
    __shared__ float tile[32][33];
    int bid = blockIdx.x, tid = threadIdx.x;
    int mode = detect_mode_inl((const u16*)adjraw);
    if (bid < 1024) {
        const u16* A = mode ? adjb : (const u16*)adjraw;
        int wave = tid >> 6, lane = tid & 63;
        int row = bid * 4 + wave;
        const u16x8* rp = (const u16x8*)(A + (size_t)row * N_NODES);
        float acc = 0.f;
#pragma unroll
        for (int it = 0; it < 8; ++it) {
            int chunk = it * 64 + lane;
            u16x8 v = rp[chunk];
            const float4* sp = (const float4*)(s + chunk * 8);
            float4 s0 = sp[0], s1 = sp[1];
            acc += b2f(v[0]) * s0.x + b2f(v[1]) * s0.y + b2f(v[2]) * s0.z + b2f(v[3]) * s0.w;
            acc += b2f(v[4]) * s1.x + b2f(v[5]) * s1.y + b2f(v[6]) * s1.z + b2f(v[7]) * s1.w;
        }
#pragma unroll
        for (int off = 32; off > 0; off >>= 1) acc += __shfl_down(acc, off);
        if (lane == 0) dv[row] = acc + 1e-5f;
    } else {
        int g = bid - 1024;
        int tx = tid & 31, ty = tid >> 5;
        int x0 = (g & 15) * 32, y0 = (g >> 4) * 32;     // x0: col in T, y0: row in T
#pragma unroll
        for (int r = ty; r < 32; r += 8) tile[r][tx] = T[(size_t)(y0 + r) * C_DIM + x0 + tx];
        __syncthreads();
        float sv = s[y0 + tx];
#pragma unroll
        for (int r = ty; r < 32; r += 8)
            TsT[(size_t)(x0 + r) * N_NODES + y0 + tx] = f2b(tile[tx][r] * sv);
    }
}

// ================= K4: gemm2 split-K partial, 128x128 m97 tile, atomic accumulate =========
// grid (32, 4, SPLITS); acc_target += (dt/EPS) * (adj @ TsT^T)_partial / d[row]
__global__ __launch_bounds__(256) void k4_gemm2(const void* __restrict__ adjraw,
        const u16* __restrict__ adjb, const u16* __restrict__ TsT,
        const float* __restrict__ dv, const float* __restrict__ dt_f,
        void* __restrict__ out, float* __restrict__ Pacc) {
    __shared__ __align__(16) u16 lA[128 * 32];   // 8 KB
    __shared__ __align__(16) u16 lB[128 * 32];   // 8 KB
    int mode = detect_mode_inl((const u16*)adjraw);
    const u16* A = mode ? adjb : (const u16*)adjraw;
    float* tgt = mode ? (float*)out : Pacc;
    int tid = threadIdx.x;
    int lane = tid & 63, wave = tid >> 6;
    int bm = blockIdx.x * 128, bn = blockIdx.y * 128;
    int kbase = blockIdx.z * KCHUNK;
    int wm = (wave & 1) * 64, wn = (wave >> 1) * 64;
    int quad = lane >> 4, l15 = lane & 15;

    const u16* Ab0 = A + (size_t)(bm + (tid >> 2)) * N_NODES + kbase + (tid & 3) * 8;
    const u16* Ab1 = A + (size_t)(bm + 64 + (tid >> 2)) * N_NODES + kbase + (tid & 3) * 8;
    const u16* Bb0 = TsT + (size_t)(bn + (tid >> 2)) * N_NODES + kbase + (tid & 3) * 8;
    const u16* Bb1 = TsT + (size_t)(bn + 64 + (tid >> 2)) * N_NODES + kbase + (tid & 3) * 8;
    u16* la0 = lA + tid * 8;  u16* la1 = lA + 2048 + tid * 8;
    u16* lb0 = lB + tid * 8;  u16* lb1 = lB + 2048 + tid * 8;

    f32x4 acc[4][4];
#pragma unroll
    for (int a = 0; a < 4; ++a)
#pragma unroll
        for (int b = 0; b < 4; ++b) acc[a][b] = (f32x4){0.f, 0.f, 0.f, 0.f};

    for (int k0 = 0; k0 < KCHUNK; k0 += 32) {
        gload16(Ab0 + k0, la0);
        gload16(Ab1 + k0, la1);
        gload16(Bb0 + k0, lb0);
        gload16(Bb1 + k0, lb1);
        __syncthreads();
        bf16x8 af[4], bfv[4];
#pragma unroll
        for (int mt = 0; mt < 4; ++mt) af[mt] = *(const bf16x8*)&lA[(wm + mt * 16 + l15) * 32 + quad * 8];
#pragma unroll
        for (int nt = 0; nt < 4; ++nt) bfv[nt] = *(const bf16x8*)&lB[(wn + nt * 16 + l15) * 32 + quad * 8];
#pragma unroll
        for (int mt = 0; mt < 4; ++mt)
#pragma unroll
            for (int nt = 0; nt < 4; ++nt)
                acc[mt][nt] = __builtin_amdgcn_mfma_f32_16x16x32_bf16(af[mt], bfv[nt], acc[mt][nt], 0, 0, 0);
        __syncthreads();
    }

    float c1 = dt_f[0] * 4.f;  // dt / EPS
#pragma unroll
    for (int mt = 0; mt < 4; ++mt) {
        float inv[4];
#pragma unroll
        for (int r = 0; r < 4; ++r) inv[r] = c1 / dv[bm + wm + mt * 16 + quad * 4 + r];
#pragma unroll
        for (int nt = 0; nt < 4; ++nt) {
            int col = bn + wn + nt * 16 + l15;
#pragma unroll
            for (int r = 0; r < 4; ++r) {
                int row = bm + wm + mt * 16 + quad * 4 + r;
                atomicAdd(&tgt[(size_t)row * C_DIM + col], acc[mt][nt][r] * inv[r]);
            }
        }
    }
}

// ================= K5: bf16 finalize (no-op in f32 mode) =================
__global__ __launch_bounds__(256) void k5_fin(const void* __restrict__ adjraw,
                                              const float* __restrict__ Pacc,
                                              u16* __restrict__ out) {
    if (detect_mode_inl((const u16*)adjraw)) return;
    int idx = blockIdx.x * 256 + threadIdx.x;
    float4 v = ((const float4*)Pacc)[idx];
    ushort4 o; o.x = f2b(v.x); o.y = f2b(v.y); o.z = f2b(v.z); o.w = f2b(v.w);
    ((ushort4*)out)[idx] = o;
}

extern "C" void kernel_launch(void* const* d_in, const int* in_sizes, int n_in,
                              void* d_out, int out_size, void* d_ws, size_t ws_size,
                              hipStream_t stream) {
    const void* x   = d_in[0];
    const void* adj = d_in[1];
    const void* Wp  = d_in[2];
    const void* bp  = d_in[3];
    const void* Wp1 = d_in[4];
    const void* bp1 = d_in[5];
    const void* Wp2 = d_in[6];
    const void* bp2 = d_in[7];
    const void* Wf  = d_in[8];
    const void* bfc = d_in[9];
    const void* dtp = d_in[10];
    const u16* adjdet = (const u16*)adj;

    char* ws = (char*)d_ws;
    float* dt_f   = (float*)(ws + OFF_DT);
    float* bias_f = (float*)(ws + OFF_BIAS);
    float* Wp_f   = (float*)(ws + OFF_WP);
    float* bp_f   = (float*)(ws + OFF_BP);
    float* Wp1_f  = (float*)(ws + OFF_WP1);
    float* bp1_f  = (float*)(ws + OFF_BP1);
    float* Wp2_f  = (float*)(ws + OFF_WP2);
    float* bp2_f  = (float*)(ws + OFF_BP2);
    float* q      = (float*)(ws + OFF_Q);
    float* s      = (float*)(ws + OFF_S);
    float* dv     = (float*)(ws + OFF_DV);
    float* T      = (float*)(ws + OFF_T);
    u16*   TsT    = (u16*)(ws + OFF_TST);
    u16*   WfT    = (u16*)(ws + OFF_WFT);
    u16*   xb     = (u16*)(ws + OFF_XB);
    u16*   adjb   = (u16*)(ws + OFF_ADJB);
    float* Pacc   = (float*)(ws + OFF_ADJB);   // bf16-mode only: adjb unused there

    k1_prep<<<3591, 256, 0, stream>>>(adj, x, Wp, bp, Wp1, bp1, Wp2, bp2, Wf, bfc, dtp,
                                      Wp_f, bp_f, Wp1_f, bp1_f, Wp2_f, bp2_f, bias_f, dt_f,
                                      adjb, q, xb, WfT);
    k2_pi_gemm1<<<1024, 256, 0, stream>>>(x, adjdet, xb, WfT,
                                          Wp_f, bp_f, Wp1_f, bp1_f, Wp2_f, bp2_f, bias_f, dt_f,
                                          q, s, T, d_out, Pacc);
    k3_mid<<<3072, 256, 0, stream>>>(adj, adjb, s, T, dv, TsT);
    k4_gemm2<<<dim3(32, 4, SPLITS), 256, 0, stream>>>(adj, adjb, TsT, dv, dt_f, d_out, Pacc);
    k5_fin<<<2048, 256, 0, stream>>>(adj, Pacc, (u16*)d_out);
}

// Round 7
// 227.513 us; speedup vs baseline: 1.1141x; 1.1141x over previous
//
#include <hip/hip_runtime.h>
#include <hip/hip_bf16.h>

#define N_NODES 4096
#define C_DIM   512
#define L_DIM   64
#define SPLITS  4
#define KCHUNK  (N_NODES / SPLITS)   // 1024

typedef unsigned short u16;
using bf16x8 = __attribute__((ext_vector_type(8))) __bf16;
using u16x8  = __attribute__((ext_vector_type(8))) unsigned short;
using f32x4  = __attribute__((ext_vector_type(4))) float;

__device__ __forceinline__ float b2f(u16 u) {
    union { unsigned int i; float f; } v; v.i = ((unsigned int)u) << 16; return v.f;
}
__device__ __forceinline__ u16 f2b(float f) {
    unsigned int u = __float_as_uint(f);
    u += 0x7fff + ((u >> 16) & 1);   // round-to-nearest-even
    return (u16)(u >> 16);
}

__device__ __forceinline__ void gload16(const u16* g, u16* l) {
    __builtin_amdgcn_global_load_lds((const __attribute__((address_space(1))) void*)g,
                                     (__attribute__((address_space(3))) void*)l,
                                     16, 0, 0);
}

// mode: 0 = inputs bf16, 1 = inputs f32. adj ~ U[0,1): bf16 u16 <= 0x3F80;
// f32 low-half u16s are random mantissa (>=0x8000 w.p. 1/2). P[err] = 2^-32.
__device__ __forceinline__ int detect_mode_inl(const u16* __restrict__ adj) {
    int m = 0;
#pragma unroll
    for (int i = 0; i < 64; ++i) m |= (adj[i] >= 0x8000) ? 1 : 0;
    return m;
}

// ---- workspace byte offsets ----
#define OFF_DT    64
#define OFF_BIAS  1024
#define OFF_WP    4096
#define OFF_BP    135168
#define OFF_WP1   135424
#define OFF_BP1   266496
#define OFF_WP2   268544
#define OFF_BP2   270592
#define OFF_Q     271360
#define OFF_S     287744
#define OFF_DV    304128
#define OFF_T     1048576
#define OFF_TST   9437184
#define OFF_WFT   13631488
#define OFF_XB    14155776
#define OFF_ADJB  18350080   // 32 MB; in bf16 mode doubles as f32 Pacc (8 MB)

__device__ __forceinline__ float ldin(const void* p, int i, int mode) {
    if (mode) return ((const float*)p)[i];
    return b2f(((const u16*)p)[i]);
}

// ================= K1: convert params | x->bf16 | adj rowsum+bf16 | Wf^T =================
// blocks: [0,263) convert, [263,2311) prep_x, [2311,3335) prep_adj, [3335,3591) trans_Wf
__global__ __launch_bounds__(256) void k1_prep(const void* __restrict__ adj, const void* __restrict__ x,
        const void* Wp, const void* bp, const void* Wp1, const void* bp1,
        const void* Wp2, const void* bp2, const void* Wf, const void* bfc, const void* dt,
        float* __restrict__ Wp_f, float* __restrict__ bp_f, float* __restrict__ Wp1_f,
        float* __restrict__ bp1_f, float* __restrict__ Wp2_f, float* __restrict__ bp2_f,
        float* __restrict__ bias_f, float* __restrict__ dt_f,
        u16* __restrict__ adjb, float* __restrict__ q, u16* __restrict__ xb,
        u16* __restrict__ WfT) {
    __shared__ float tile[32][33];
    int bid = blockIdx.x, tid = threadIdx.x;
    int mode = detect_mode_inl((const u16*)adj);
    if (bid < 263) {
        int idx = bid * 256 + tid;
        if (idx < 32768)        Wp_f[idx]          = ldin(Wp,  idx, mode);
        else if (idx < 32832)   bp_f[idx - 32768]  = ldin(bp,  idx - 32768, mode);
        else if (idx < 65600)   Wp1_f[idx - 32832] = ldin(Wp1, idx - 32832, mode);
        else if (idx < 66112)   bp1_f[idx - 65600] = ldin(bp1, idx - 65600, mode);
        else if (idx < 66624)   Wp2_f[idx - 66112] = ldin(Wp2, idx - 66112, mode);
        else if (idx == 66624)  bp2_f[0]           = ldin(bp2, 0, mode);
        else if (idx < 67137)   bias_f[idx - 66625] = ldin(bfc, idx - 66625, mode);
        else if (idx == 67137)  dt_f[0]            = ldin(dt, 0, mode);
    } else if (bid < 2311) {
        if (mode == 0) return;
        int idx = (bid - 263) * 256 + tid;
        float4 v = ((const float4*)x)[idx];
        ushort4 o; o.x = f2b(v.x); o.y = f2b(v.y); o.z = f2b(v.z); o.w = f2b(v.w);
        ((ushort4*)xb)[idx] = o;
    } else if (bid < 3335) {
        int wave = tid >> 6, lane = tid & 63;
        int row = (bid - 2311) * 4 + wave;
        float acc = 0.f;
        if (mode) {
            const float4* rp = (const float4*)((const float*)adj + (size_t)row * N_NODES);
            ushort4* wp = (ushort4*)(adjb + (size_t)row * N_NODES);
#pragma unroll
            for (int it = 0; it < 16; ++it) {
                float4 v = rp[it * 64 + lane];
                acc += v.x + v.y + v.z + v.w;
                ushort4 o; o.x = f2b(v.x); o.y = f2b(v.y); o.z = f2b(v.z); o.w = f2b(v.w);
                wp[it * 64 + lane] = o;
            }
        } else {
            const u16x8* rp = (const u16x8*)((const u16*)adj + (size_t)row * N_NODES);
#pragma unroll
            for (int it = 0; it < 8; ++it) {
                u16x8 v = rp[it * 64 + lane];
#pragma unroll
                for (int e = 0; e < 8; ++e) acc += b2f(v[e]);
            }
        }
#pragma unroll
        for (int off = 32; off > 0; off >>= 1) acc += __shfl_down(acc, off);
        if (lane == 0) q[row] = acc;
    } else {
        int g = bid - 3335;
        int tx = tid & 31, ty = tid >> 5;
        int x0 = (g & 15) * 32, y0 = (g >> 4) * 32;
        if (mode) {
            const float* src = (const float*)Wf;
#pragma unroll
            for (int r = ty; r < 32; r += 8) tile[r][tx] = src[(size_t)(y0 + r) * C_DIM + x0 + tx];
        } else {
            const u16* src = (const u16*)Wf;
#pragma unroll
            for (int r = ty; r < 32; r += 8) tile[r][tx] = b2f(src[(size_t)(y0 + r) * C_DIM + x0 + tx]);
        }
        __syncthreads();
#pragma unroll
        for (int r = ty; r < 32; r += 8)
            WfT[(size_t)(x0 + r) * C_DIM + y0 + tx] = f2b(tile[tx][r]);
    }
}

// ================= K2: pi-MLP (blocks [0,512)) | gemm1 relu(x@Wf+b) (blocks [512,1024)) ====
// gemm1 epilogue also writes tgt = (1-dt)*T (the accumulator init for k4's atomics)
__global__ __launch_bounds__(256) void k2_pi_gemm1(const void* __restrict__ xraw,
        const u16* __restrict__ adjdet, const u16* __restrict__ xb, const u16* __restrict__ WfT,
        const float* __restrict__ Wp_f,  const float* __restrict__ bp_f,
        const float* __restrict__ Wp1_f, const float* __restrict__ bp1_f,
        const float* __restrict__ Wp2_f, const float* __restrict__ bp2_f,
        const float* __restrict__ bias_f, const float* __restrict__ dt_f,
        const float* __restrict__ q, float* __restrict__ s, float* __restrict__ T,
        void* __restrict__ out, float* __restrict__ Pacc) {
    __shared__ __align__(16) char smem[18560];
    int bid = blockIdx.x, tid = threadIdx.x;
    int mode = detect_mode_inl(adjdet);
    if (bid < 512) {
        float (*sx)[C_DIM] = (float(*)[C_DIM])smem;
        float (*sz)[L_DIM] = (float(*)[L_DIM])(smem + 16384);
        float (*red)[8]    = (float(*)[8])(smem + 18432);
        int i0 = bid * 8;
        // x as bf16 in both modes (xb is the f32-mode copy; x itself in bf16 mode)
        const u16* xsrc = mode ? xb : (const u16*)xraw;
        const u16x8* xp = (const u16x8*)(xsrc + (size_t)i0 * C_DIM);
#pragma unroll
        for (int r = 0; r < 2; ++r) {
            u16x8 v = xp[tid + 256 * r];
            float* dstf = &sx[0][0] + (size_t)(tid + 256 * r) * 8;
#pragma unroll
            for (int e = 0; e < 8; ++e) dstf[e] = b2f(v[e]);
        }
        __syncthreads();
        int j = tid & 63, n0 = tid >> 6;
        float a0 = 0.f, a1 = 0.f;
#pragma unroll 4
        for (int k = 0; k < C_DIM; ++k) {
            float w = Wp_f[k * L_DIM + j];
            a0 += sx[n0][k] * w;
            a1 += sx[n0 + 4][k] * w;
        }
        sz[n0][j] = a0 + bp_f[j];
        sz[n0 + 4][j] = a1 + bp_f[j];
        __syncthreads();
        int m0 = tid, m1 = tid + 256;
        float b0 = bp1_f[m0], b1 = bp1_f[m1];
        float h0[8], h1[8];
#pragma unroll
        for (int n = 0; n < 8; ++n) { h0[n] = b0; h1[n] = b1; }
#pragma unroll 8
        for (int jj = 0; jj < L_DIM; ++jj) {
            float w0 = Wp1_f[jj * C_DIM + m0];
            float w1 = Wp1_f[jj * C_DIM + m1];
#pragma unroll
            for (int n = 0; n < 8; ++n) {
                float z = sz[n][jj];
                h0[n] += z * w0;
                h1[n] += z * w1;
            }
        }
        float w2a = Wp2_f[m0], w2b = Wp2_f[m1];
        float p[8];
#pragma unroll
        for (int n = 0; n < 8; ++n)
            p[n] = fmaxf(h0[n], 0.f) * w2a + fmaxf(h1[n], 0.f) * w2b;
#pragma unroll
        for (int off = 32; off > 0; off >>= 1)
#pragma unroll
            for (int n = 0; n < 8; ++n) p[n] += __shfl_down(p[n], off);
        int lane = tid & 63, wave = tid >> 6;
        if (lane == 0) {
#pragma unroll
            for (int n = 0; n < 8; ++n) red[wave][n] = p[n];
        }
        __syncthreads();
        if (tid < 8) {
            float tot = red[0][tid] + red[1][tid] + red[2][tid] + red[3][tid] + bp2_f[0];
            float pi = 1.f / (1.f + expf(-tot));
            s[i0 + tid] = pi / q[i0 + tid];
        }
    } else {
        // gemm1: 64x64 tile, A = x (bf16), B = WfT, K = 512; T = relu(acc + bias)
        u16* lA = (u16*)smem;
        u16* lB = (u16*)(smem + 4096);
        const u16* A = mode ? xb : (const u16*)xraw;
        float* tgt = mode ? (float*)out : Pacc;
        int g = bid - 512;
        int lane = tid & 63, wave = tid >> 6;
        int bm = (g & 63) * 64, bn = (g >> 6) * 64;
        int quad = lane >> 4, l15 = lane & 15;
        int wm = wave * 16;
        const u16* Ap = A + (size_t)(bm + (tid >> 2)) * C_DIM + (tid & 3) * 8;
        const u16* Bp = WfT + (size_t)(bn + (tid >> 2)) * C_DIM + (tid & 3) * 8;
        u16* la = lA + tid * 8;
        u16* lb = lB + tid * 8;
        f32x4 acc[4];
#pragma unroll
        for (int nt = 0; nt < 4; ++nt) acc[nt] = (f32x4){0.f, 0.f, 0.f, 0.f};
        for (int k0 = 0; k0 < C_DIM; k0 += 32) {
            gload16(Ap + k0, la);
            gload16(Bp + k0, lb);
            __syncthreads();
            bf16x8 af = *(const bf16x8*)&lA[(wm + l15) * 32 + quad * 8];
            bf16x8 bfv[4];
#pragma unroll
            for (int nt = 0; nt < 4; ++nt) bfv[nt] = *(const bf16x8*)&lB[(nt * 16 + l15) * 32 + quad * 8];
#pragma unroll
            for (int nt = 0; nt < 4; ++nt)
                acc[nt] = __builtin_amdgcn_mfma_f32_16x16x32_bf16(af, bfv[nt], acc[nt], 0, 0, 0);
            __syncthreads();
        }
        float c0 = 1.f - dt_f[0];
#pragma unroll
        for (int nt = 0; nt < 4; ++nt) {
            int col = bn + nt * 16 + l15;
            float bv = bias_f[col];
#pragma unroll
            for (int r = 0; r < 4; ++r) {
                int row = bm + wm + quad * 4 + r;
                float t = fmaxf(acc[nt][r] + bv, 0.f);
                T[(size_t)row * C_DIM + col] = t;
                tgt[(size_t)row * C_DIM + col] = c0 * t;
            }
        }
    }
}

// ================= K3: dvec [0,1024) | trans_scale [1024,3072) =================
__global__ __launch_bounds__(256) void k3_mid(const void* __restrict__ adjraw,
        const u16* __restrict__ adjb, const float* __restrict__ s,
        const float* __restrict__ T,
        float* __restrict__ dv, u16* __restrict__ TsT) {
    __shared__ float tile[32][33];
    int bid = blockIdx.x, tid = threadIdx.x;
    int mode = detect_mode_inl((const u16*)adjraw);
    if (bid < 1024) {
        const u16* A = mode ? adjb : (const u16*)adjraw;
        int wave = tid >> 6, lane = tid & 63;
        int row = bid * 4 + wave;
        const u16x8* rp = (const u16x8*)(A + (size_t)row * N_NODES);
        float acc = 0.f;
#pragma unroll
        for (int it = 0; it < 8; ++it) {
            int chunk = it * 64 + lane;
            u16x8 v = rp[chunk];
            const float4* sp = (const float4*)(s + chunk * 8);
            float4 s0 = sp[0], s1 = sp[1];
            acc += b2f(v[0]) * s0.x + b2f(v[1]) * s0.y + b2f(v[2]) * s0.z + b2f(v[3]) * s0.w;
            acc += b2f(v[4]) * s1.x + b2f(v[5]) * s1.y + b2f(v[6]) * s1.z + b2f(v[7]) * s1.w;
        }
#pragma unroll
        for (int off = 32; off > 0; off >>= 1) acc += __shfl_down(acc, off);
        if (lane == 0) dv[row] = acc + 1e-5f;
    } else {
        int g = bid - 1024;
        int tx = tid & 31, ty = tid >> 5;
        int x0 = (g & 15) * 32, y0 = (g >> 4) * 32;     // x0: col in T, y0: row in T
#pragma unroll
        for (int r = ty; r < 32; r += 8) tile[r][tx] = T[(size_t)(y0 + r) * C_DIM + x0 + tx];
        __syncthreads();
        float sv = s[y0 + tx];
#pragma unroll
        for (int r = ty; r < 32; r += 8)
            TsT[(size_t)(x0 + r) * N_NODES + y0 + tx] = f2b(tile[tx][r] * sv);
    }
}

// ================= K4: gemm2 split-K partial, 128x128 tile, BK=64 (two m97 32-K subtiles),
// atomic accumulate. grid (32, 4, SPLITS); tgt += (dt/EPS) * (adj @ TsT^T)_partial / d[row]
__global__ __launch_bounds__(256) void k4_gemm2(const void* __restrict__ adjraw,
        const u16* __restrict__ adjb, const u16* __restrict__ TsT,
        const float* __restrict__ dv, const float* __restrict__ dt_f,
        void* __restrict__ out, float* __restrict__ Pacc) {
    // Two independent 8 KB subtiles per operand (k 0..31 and k 32..63), each in the
    // verified m97 layout (row stride 32 u16 = 64 B). Keeps global_load_lds lane
    // contiguity AND m97 bank behavior, while halving barrier count vs BK=32.
    __shared__ __align__(16) u16 lA[8192];   // 16 KB: [0..4095] k-sub 0, [4096..8191] k-sub 1
    __shared__ __align__(16) u16 lB[8192];   // 16 KB
    int mode = detect_mode_inl((const u16*)adjraw);
    const u16* A = mode ? adjb : (const u16*)adjraw;
    float* tgt = mode ? (float*)out : Pacc;
    int tid = threadIdx.x;
    int lane = tid & 63, wave = tid >> 6;
    int bm = blockIdx.x * 128, bn = blockIdx.y * 128;
    int kbase = blockIdx.z * KCHUNK;
    int wm = (wave & 1) * 64, wn = (wave >> 1) * 64;
    int quad = lane >> 4, l15 = lane & 15;

    const u16* Ab0 = A + (size_t)(bm + (tid >> 2)) * N_NODES + kbase + (tid & 3) * 8;
    const u16* Ab1 = A + (size_t)(bm + 64 + (tid >> 2)) * N_NODES + kbase + (tid & 3) * 8;
    const u16* Bb0 = TsT + (size_t)(bn + (tid >> 2)) * N_NODES + kbase + (tid & 3) * 8;
    const u16* Bb1 = TsT + (size_t)(bn + 64 + (tid >> 2)) * N_NODES + kbase + (tid & 3) * 8;
    u16* la00 = lA + tid * 8;        u16* la01 = lA + 2048 + tid * 8;   // k-sub 0
    u16* la10 = lA + 4096 + tid * 8; u16* la11 = lA + 6144 + tid * 8;   // k-sub 1
    u16* lb00 = lB + tid * 8;        u16* lb01 = lB + 2048 + tid * 8;
    u16* lb10 = lB + 4096 + tid * 8; u16* lb11 = lB + 6144 + tid * 8;

    f32x4 acc[4][4];
#pragma unroll
    for (int a = 0; a < 4; ++a)
#pragma unroll
        for (int b = 0; b < 4; ++b) acc[a][b] = (f32x4){0.f, 0.f, 0.f, 0.f};

    for (int k0 = 0; k0 < KCHUNK; k0 += 64) {
        gload16(Ab0 + k0, la00);
        gload16(Ab1 + k0, la01);
        gload16(Ab0 + k0 + 32, la10);
        gload16(Ab1 + k0 + 32, la11);
        gload16(Bb0 + k0, lb00);
        gload16(Bb1 + k0, lb01);
        gload16(Bb0 + k0 + 32, lb10);
        gload16(Bb1 + k0 + 32, lb11);
        __syncthreads();
#pragma unroll
        for (int kk = 0; kk < 2; ++kk) {
            const u16* baseA = lA + kk * 4096;
            const u16* baseB = lB + kk * 4096;
            bf16x8 af[4], bfv[4];
#pragma unroll
            for (int mt = 0; mt < 4; ++mt) af[mt] = *(const bf16x8*)&baseA[(wm + mt * 16 + l15) * 32 + quad * 8];
#pragma unroll
            for (int nt = 0; nt < 4; ++nt) bfv[nt] = *(const bf16x8*)&baseB[(wn + nt * 16 + l15) * 32 + quad * 8];
#pragma unroll
            for (int mt = 0; mt < 4; ++mt)
#pragma unroll
                for (int nt = 0; nt < 4; ++nt)
                    acc[mt][nt] = __builtin_amdgcn_mfma_f32_16x16x32_bf16(af[mt], bfv[nt], acc[mt][nt], 0, 0, 0);
        }
        __syncthreads();
    }

    float c1 = dt_f[0] * 4.f;  // dt / EPS
#pragma unroll
    for (int mt = 0; mt < 4; ++mt) {
        float inv[4];
#pragma unroll
        for (int r = 0; r < 4; ++r) inv[r] = c1 / dv[bm + wm + mt * 16 + quad * 4 + r];
#pragma unroll
        for (int nt = 0; nt < 4; ++nt) {
            int col = bn + wn + nt * 16 + l15;
#pragma unroll
            for (int r = 0; r < 4; ++r) {
                int row = bm + wm + mt * 16 + quad * 4 + r;
                atomicAdd(&tgt[(size_t)row * C_DIM + col], acc[mt][nt][r] * inv[r]);
            }
        }
    }
}

// ================= K5: bf16 finalize (no-op in f32 mode) =================
__global__ __launch_bounds__(256) void k5_fin(const void* __restrict__ adjraw,
                                              const float* __restrict__ Pacc,
                                              u16* __restrict__ out) {
    if (detect_mode_inl((const u16*)adjraw)) return;
    int idx = blockIdx.x * 256 + threadIdx.x;
    float4 v = ((const float4*)Pacc)[idx];
    ushort4 o; o.x = f2b(v.x); o.y = f2b(v.y); o.z = f2b(v.z); o.w = f2b(v.w);
    ((ushort4*)out)[idx] = o;
}

extern "C" void kernel_launch(void* const* d_in, const int* in_sizes, int n_in,
                              void* d_out, int out_size, void* d_ws, size_t ws_size,
                              hipStream_t stream) {
    const void* x   = d_in[0];
    const void* adj = d_in[1];
    const void* Wp  = d_in[2];
    const void* bp  = d_in[3];
    const void* Wp1 = d_in[4];
    const void* bp1 = d_in[5];
    const void* Wp2 = d_in[6];
    const void* bp2 = d_in[7];
    const void* Wf  = d_in[8];
    const void* bfc = d_in[9];
    const void* dtp = d_in[10];
    const u16* adjdet = (const u16*)adj;

    char* ws = (char*)d_ws;
    float* dt_f   = (float*)(ws + OFF_DT);
    float* bias_f = (float*)(ws + OFF_BIAS);
    float* Wp_f   = (float*)(ws + OFF_WP);
    float* bp_f   = (float*)(ws + OFF_BP);
    float* Wp1_f  = (float*)(ws + OFF_WP1);
    float* bp1_f  = (float*)(ws + OFF_BP1);
    float* Wp2_f  = (float*)(ws + OFF_WP2);
    float* bp2_f  = (float*)(ws + OFF_BP2);
    float* q      = (float*)(ws + OFF_Q);
    float* s      = (float*)(ws + OFF_S);
    float* dv     = (float*)(ws + OFF_DV);
    float* T      = (float*)(ws + OFF_T);
    u16*   TsT    = (u16*)(ws + OFF_TST);
    u16*   WfT    = (u16*)(ws + OFF_WFT);
    u16*   xb     = (u16*)(ws + OFF_XB);
    u16*   adjb   = (u16*)(ws + OFF_ADJB);
    float* Pacc   = (float*)(ws + OFF_ADJB);   // bf16-mode only: adjb unused there

    k1_prep<<<3591, 256, 0, stream>>>(adj, x, Wp, bp, Wp1, bp1, Wp2, bp2, Wf, bfc, dtp,
                                      Wp_f, bp_f, Wp1_f, bp1_f, Wp2_f, bp2_f, bias_f, dt_f,
                                      adjb, q, xb, WfT);
    k2_pi_gemm1<<<1024, 256, 0, stream>>>(x, adjdet, xb, WfT,
                                          Wp_f, bp_f, Wp1_f, bp1_f, Wp2_f, bp2_f, bias_f, dt_f,
                                          q, s, T, d_out, Pacc);
    k3_mid<<<3072, 256, 0, stream>>>(adj, adjb, s, T, dv, TsT);
    k4_gemm2<<<dim3(32, 4, SPLITS), 256, 0, stream>>>(adj, adjb, TsT, dv, dt_f, d_out, Pacc);
    k5_fin<<<2048, 256, 0, stream>>>(adj, Pacc, (u16*)d_out);
}

// Round 9
// 214.755 us; speedup vs baseline: 1.1803x; 1.0594x over previous
//
#include <hip/hip_runtime.h>
#include <hip/hip_bf16.h>

#define N_NODES 4096
#define C_DIM   512
#define L_DIM   64
#define SPLITS  4
#define KCHUNK  (N_NODES / SPLITS)   // 1024

typedef unsigned short u16;
typedef unsigned int   u32;
using bf16x8 = __attribute__((ext_vector_type(8))) __bf16;
using u16x8  = __attribute__((ext_vector_type(8))) unsigned short;
using f32x4  = __attribute__((ext_vector_type(4))) float;

__device__ __forceinline__ float b2f(u16 u) {
    union { unsigned int i; float f; } v; v.i = ((unsigned int)u) << 16; return v.f;
}
__device__ __forceinline__ u16 f2b(float f) {
    unsigned int u = __float_as_uint(f);
    u += 0x7fff + ((u >> 16) & 1);   // round-to-nearest-even
    return (u16)(u >> 16);
}
__device__ __forceinline__ void gload16(const void* g, void* l) {
    __builtin_amdgcn_global_load_lds((const __attribute__((address_space(1))) void*)g,
                                     (__attribute__((address_space(3))) void*)l,
                                     16, 0, 0);
}
// mode: 0 = bf16 inputs, 1 = f32. adj ~ U[0,1): bf16 u16 <= 0x3F80; f32 low-halves random.
__device__ __forceinline__ int detect_mode_inl(const u16* __restrict__ adj) {
    int m = 0;
#pragma unroll
    for (int i = 0; i < 64; ++i) m |= (adj[i] >= 0x8000) ? 1 : 0;
    return m;
}

// ---- workspace byte offsets ----
#define OFF_MODE  0
#define OFF_DT    64
#define OFF_BIAS  1024      // 512 f32
#define OFF_BP    4096      // 64 f32
#define OFF_BP1   4608      // 512 f32
#define OFF_WP2   8192      // 512 f32
#define OFF_BP2   10240     // 1 f32
#define OFF_Q     16384
#define OFF_S     32768
#define OFF_DV    49152
#define OFF_WPP   65536     // 16384 u32: packed bf16 k-pairs of Wp
#define OFF_WP1P  131072    // 16384 u32: packed bf16 k-pairs of Wp1
#define OFF_WFT   196608    // 512 KB bf16 Wf^T
#define OFF_T     1048576   // 8 MB f32
#define OFF_TST   9437184   // 4 MB bf16 TsT[c][j]
#define OFF_XB    13631488  // 4 MB bf16 x
#define OFF_ADJB  17825792  // 32 MB bf16 adj (f32 mode); doubles as Pacc (bf16 mode)

__device__ __forceinline__ float ldin(const void* p, int i, int mode) {
    if (mode) return ((const float*)p)[i];
    return b2f(((const u16*)p)[i]);
}

// ================= K1: smalls | x->bf16 | adj rowsum (+bf16 copy in f32 mode) | Wf^T |
//                     pack Wp | pack Wp1 ====
// blocks: [0,7) smalls, [7,2055) prep_x, [2055,3079) prep_adj, [3079,3335) trans_Wf,
//         [3335,3399) packWp, [3399,3463) packWp1
__global__ __launch_bounds__(256) void k1_prep(const void* __restrict__ adj, const void* __restrict__ x,
        const void* Wp, const void* bp, const void* Wp1, const void* bp1,
        const void* Wp2, const void* bp2, const void* Wf, const void* bfc, const void* dt,
        int* __restrict__ modep,
        float* __restrict__ bp_f, float* __restrict__ bp1_f,
        float* __restrict__ Wp2_f, float* __restrict__ bp2_f,
        float* __restrict__ bias_f, float* __restrict__ dt_f,
        u32* __restrict__ WpP, u32* __restrict__ Wp1P,
        u16* __restrict__ adjb, float* __restrict__ q, u16* __restrict__ xb,
        u16* __restrict__ WfT) {
    __shared__ float tile[32][33];
    int bid = blockIdx.x, tid = threadIdx.x;
    int mode = detect_mode_inl((const u16*)adj);
    if (bid < 7) {
        if (bid == 0 && tid == 0) *modep = mode;
        int idx = bid * 256 + tid;
        if (idx < 64)           bp_f[idx]          = ldin(bp,  idx, mode);
        else if (idx < 576)     bp1_f[idx - 64]    = ldin(bp1, idx - 64, mode);
        else if (idx < 1088)    Wp2_f[idx - 576]   = ldin(Wp2, idx - 576, mode);
        else if (idx == 1088)   bp2_f[0]           = ldin(bp2, 0, mode);
        else if (idx < 1601)    bias_f[idx - 1089] = ldin(bfc, idx - 1089, mode);
        else if (idx == 1601)   dt_f[0]            = ldin(dt, 0, mode);
    } else if (bid < 2055) {
        if (mode == 0) return;
        int idx = (bid - 7) * 256 + tid;
        float4 v = ((const float4*)x)[idx];
        ushort4 o; o.x = f2b(v.x); o.y = f2b(v.y); o.z = f2b(v.z); o.w = f2b(v.w);
        ((ushort4*)xb)[idx] = o;
    } else if (bid < 3079) {
        int wave = tid >> 6, lane = tid & 63;
        int row = (bid - 2055) * 4 + wave;
        float acc = 0.f;
        if (mode) {
            const float4* rp = (const float4*)((const float*)adj + (size_t)row * N_NODES);
            ushort4* wp = (ushort4*)(adjb + (size_t)row * N_NODES);
#pragma unroll
            for (int it = 0; it < 16; ++it) {
                float4 v = rp[it * 64 + lane];
                acc += v.x + v.y + v.z + v.w;
                ushort4 o; o.x = f2b(v.x); o.y = f2b(v.y); o.z = f2b(v.z); o.w = f2b(v.w);
                wp[it * 64 + lane] = o;
            }
        } else {
            const u16x8* rp = (const u16x8*)((const u16*)adj + (size_t)row * N_NODES);
#pragma unroll
            for (int it = 0; it < 8; ++it) {
                u16x8 v = rp[it * 64 + lane];
#pragma unroll
                for (int e = 0; e < 8; ++e) acc += b2f(v[e]);
            }
        }
#pragma unroll
        for (int off = 32; off > 0; off >>= 1) acc += __shfl_down(acc, off);
        if (lane == 0) q[row] = acc;
    } else if (bid < 3335) {
        int g = bid - 3079;
        int tx = tid & 31, ty = tid >> 5;
        int x0 = (g & 15) * 32, y0 = (g >> 4) * 32;
        if (mode) {
            const float* src = (const float*)Wf;
#pragma unroll
            for (int r = ty; r < 32; r += 8) tile[r][tx] = src[(size_t)(y0 + r) * C_DIM + x0 + tx];
        } else {
            const u16* src = (const u16*)Wf;
#pragma unroll
            for (int r = ty; r < 32; r += 8) tile[r][tx] = b2f(src[(size_t)(y0 + r) * C_DIM + x0 + tx]);
        }
        __syncthreads();
#pragma unroll
        for (int r = ty; r < 32; r += 8)
            WfT[(size_t)(x0 + r) * C_DIM + y0 + tx] = f2b(tile[tx][r]);
    } else if (bid < 3399) {
        // WpP[k2*64 + j] = pack(Wp[2k2][j], Wp[2k2+1][j])
        int idx = (bid - 3335) * 256 + tid;              // 0..16383
        int k2i = idx >> 6, j = idx & 63;
        float a = ldin(Wp, (2 * k2i) * L_DIM + j, mode);
        float b = ldin(Wp, (2 * k2i + 1) * L_DIM + j, mode);
        WpP[idx] = (u32)f2b(a) | ((u32)f2b(b) << 16);
    } else {
        // Wp1P[jj2*512 + m] = pack(Wp1[2jj2][m], Wp1[2jj2+1][m])
        int idx = (bid - 3399) * 256 + tid;              // 0..16383
        int jj2 = idx >> 9, m = idx & 511;
        float a = ldin(Wp1, (2 * jj2) * C_DIM + m, mode);
        float b = ldin(Wp1, (2 * jj2 + 1) * C_DIM + m, mode);
        Wp1P[idx] = (u32)f2b(a) | ((u32)f2b(b) << 16);
    }
}

// ================= K2: pi-MLP [0,512) | gemm1 relu(x@Wf+b) [512,1024) =================
__global__ __launch_bounds__(256) void k2_pi_gemm1(const void* __restrict__ xraw,
        const int* __restrict__ modep, const u16* __restrict__ xb, const u16* __restrict__ WfT,
        const u32* __restrict__ WpP, const u32* __restrict__ Wp1P,
        const float* __restrict__ bp_f,  const float* __restrict__ bp1_f,
        const float* __restrict__ Wp2_f, const float* __restrict__ bp2_f,
        const float* __restrict__ bias_f, const float* __restrict__ dt_f,
        const float* __restrict__ q, float* __restrict__ s, float* __restrict__ T,
        void* __restrict__ out, float* __restrict__ Pacc) {
    __shared__ __align__(16) char smem[26880];
    int bid = blockIdx.x, tid = threadIdx.x;
    int mode = *modep;
    if (bid < 512) {
        float (*sx)[C_DIM]      = (float(*)[C_DIM])smem;                 // 16 KB
        float (*red)[8][L_DIM]  = (float(*)[8][L_DIM])(smem + 16384);    // 8 KB
        float (*sz)[L_DIM]      = (float(*)[L_DIM])(smem + 24576);       // 2 KB
        float (*rw)[8]          = (float(*)[8])(smem + 26624);           // 128 B
        int i0 = bid * 8;
        const u16* xsrc = mode ? xb : (const u16*)xraw;
        const u16x8* xp = (const u16x8*)(xsrc + (size_t)i0 * C_DIM);
#pragma unroll
        for (int r = 0; r < 2; ++r) {
            u16x8 v = xp[tid + 256 * r];
            float* dstf = &sx[0][0] + (size_t)(tid + 256 * r) * 8;
#pragma unroll
            for (int e = 0; e < 8; ++e) dstf[e] = b2f(v[e]);
        }
        __syncthreads();
        // z-phase: thread (part = tid>>6, j = tid&63) covers k in [part*128, +128)
        int j = tid & 63, part = tid >> 6;
        float za[8];
#pragma unroll
        for (int n = 0; n < 8; ++n) za[n] = 0.f;
        const u32* wp = WpP + part * 4096 + j;
#pragma unroll 8
        for (int kk = 0; kk < 64; ++kk) {
            u32 w = wp[kk * 64];
            float wa = b2f((u16)(w & 0xFFFF)), wb = b2f((u16)(w >> 16));
            int k = part * 128 + kk * 2;
#pragma unroll
            for (int n = 0; n < 8; ++n) za[n] += sx[n][k] * wa + sx[n][k + 1] * wb;
        }
#pragma unroll
        for (int n = 0; n < 8; ++n) red[part][n][j] = za[n];
        __syncthreads();
#pragma unroll
        for (int r = 0; r < 2; ++r) {
            int idx = tid + r * 256; int n = idx >> 6, jj = idx & 63;
            sz[n][jj] = red[0][n][jj] + red[1][n][jj] + red[2][n][jj] + red[3][n][jj] + bp_f[jj];
        }
        __syncthreads();
        // h-phase: thread owns m0 = tid, m1 = tid+256
        int m0 = tid, m1 = tid + 256;
        float h0[8], h1[8];
        float b0 = bp1_f[m0], b1 = bp1_f[m1];
#pragma unroll
        for (int n = 0; n < 8; ++n) { h0[n] = b0; h1[n] = b1; }
        const u32* w1p = Wp1P + m0;
#pragma unroll 4
        for (int jj2 = 0; jj2 < 32; ++jj2) {
            u32 w0 = w1p[jj2 * 512], w1 = w1p[jj2 * 512 + 256];
            float w0a = b2f((u16)(w0 & 0xFFFF)), w0b = b2f((u16)(w0 >> 16));
            float w1a = b2f((u16)(w1 & 0xFFFF)), w1b = b2f((u16)(w1 >> 16));
#pragma unroll
            for (int n = 0; n < 8; ++n) {
                float za_ = sz[n][2 * jj2], zb_ = sz[n][2 * jj2 + 1];
                h0[n] += za_ * w0a + zb_ * w0b;
                h1[n] += za_ * w1a + zb_ * w1b;
            }
        }
        float w2a = Wp2_f[m0], w2b = Wp2_f[m1];
        float p[8];
#pragma unroll
        for (int n = 0; n < 8; ++n)
            p[n] = fmaxf(h0[n], 0.f) * w2a + fmaxf(h1[n], 0.f) * w2b;
#pragma unroll
        for (int off = 32; off > 0; off >>= 1)
#pragma unroll
            for (int n = 0; n < 8; ++n) p[n] += __shfl_down(p[n], off);
        int lane = tid & 63, wave = tid >> 6;
        if (lane == 0) {
#pragma unroll
            for (int n = 0; n < 8; ++n) rw[wave][n] = p[n];
        }
        __syncthreads();
        if (tid < 8) {
            float tot = rw[0][tid] + rw[1][tid] + rw[2][tid] + rw[3][tid] + bp2_f[0];
            float pi = 1.f / (1.f + expf(-tot));
            s[i0 + tid] = pi / q[i0 + tid];
        }
    } else {
        // gemm1: 64x64 tile, K=512; T = relu(acc+bias), tgt = (1-dt)*T
        u16* lA = (u16*)smem;
        u16* lB = (u16*)(smem + 4096);
        const u16* A = mode ? xb : (const u16*)xraw;
        float* tgt = mode ? (float*)out : Pacc;
        int g = bid - 512;
        int lane = tid & 63, wave = tid >> 6;
        int bm = (g & 63) * 64, bn = (g >> 6) * 64;
        int quad = lane >> 4, l15 = lane & 15;
        int wm = wave * 16;
        const u16* Ap = A + (size_t)(bm + (tid >> 2)) * C_DIM + (tid & 3) * 8;
        const u16* Bp = WfT + (size_t)(bn + (tid >> 2)) * C_DIM + (tid & 3) * 8;
        u16* la = lA + tid * 8;
        u16* lb = lB + tid * 8;
        f32x4 acc[4];
#pragma unroll
        for (int nt = 0; nt < 4; ++nt) acc[nt] = (f32x4){0.f, 0.f, 0.f, 0.f};
        for (int k0 = 0; k0 < C_DIM; k0 += 32) {
            gload16(Ap + k0, la);
            gload16(Bp + k0, lb);
            __syncthreads();
            bf16x8 af = *(const bf16x8*)&lA[(wm + l15) * 32 + quad * 8];
            bf16x8 bfv[4];
#pragma unroll
            for (int nt = 0; nt < 4; ++nt) bfv[nt] = *(const bf16x8*)&lB[(nt * 16 + l15) * 32 + quad * 8];
#pragma unroll
            for (int nt = 0; nt < 4; ++nt)
                acc[nt] = __builtin_amdgcn_mfma_f32_16x16x32_bf16(af, bfv[nt], acc[nt], 0, 0, 0);
            __syncthreads();
        }
        float c0 = 1.f - dt_f[0];
#pragma unroll
        for (int nt = 0; nt < 4; ++nt) {
            int col = bn + nt * 16 + l15;
            float bv = bias_f[col];
#pragma unroll
            for (int r = 0; r < 4; ++r) {
                int row = bm + wm + quad * 4 + r;
                float t = fmaxf(acc[nt][r] + bv, 0.f);
                T[(size_t)row * C_DIM + col] = t;
                tgt[(size_t)row * C_DIM + col] = c0 * t;
            }
        }
    }
}

// ================= K3: dvec [0,1024) | trans_scale -> bf16 [1024,3072) =================
__global__ __launch_bounds__(256) void k3_mid(const void* __restrict__ adjraw,
        const int* __restrict__ modep,
        const u16* __restrict__ adjb, const float* __restrict__ s,
        const float* __restrict__ T,
        float* __restrict__ dv, u16* __restrict__ TsT) {
    __shared__ float tile[32][33];
    int bid = blockIdx.x, tid = threadIdx.x;
    int mode = *modep;
    if (bid < 1024) {
        const u16* A = mode ? adjb : (const u16*)adjraw;
        int wave = tid >> 6, lane = tid & 63;
        int row = bid * 4 + wave;
        const u16x8* rp = (const u16x8*)(A + (size_t)row * N_NODES);
        float acc = 0.f;
#pragma unroll
        for (int it = 0; it < 8; ++it) {
            int chunk = it * 64 + lane;
            u16x8 v = rp[chunk];
            const float4* sp = (const float4*)(s + chunk * 8);
            float4 s0 = sp[0], s1 = sp[1];
            acc += b2f(v[0]) * s0.x + b2f(v[1]) * s0.y + b2f(v[2]) * s0.z + b2f(v[3]) * s0.w;
            acc += b2f(v[4]) * s1.x + b2f(v[5]) * s1.y + b2f(v[6]) * s1.z + b2f(v[7]) * s1.w;
        }
#pragma unroll
        for (int off = 32; off > 0; off >>= 1) acc += __shfl_down(acc, off);
        if (lane == 0) dv[row] = acc + 1e-5f;
    } else {
        int g = bid - 1024;
        int tx = tid & 31, ty = tid >> 5;
        int x0 = (g & 15) * 32, y0 = (g >> 4) * 32;     // x0: col in T, y0: row in T
#pragma unroll
        for (int r = ty; r < 32; r += 8) tile[r][tx] = T[(size_t)(y0 + r) * C_DIM + x0 + tx];
        __syncthreads();
        float sv = s[y0 + tx];
#pragma unroll
        for (int r = ty; r < 32; r += 8)
            TsT[(size_t)(x0 + r) * N_NODES + y0 + tx] = f2b(tile[tx][r] * sv);
    }
}

// ================= K4: gemm2 split-K partial, 128x128 tile, BK=64 (two m97 32-K subtiles),
// atomic accumulate. grid (32, 4, SPLITS); tgt += (dt/EPS) * (adj @ TsT^T)_partial / d[row]
__global__ __launch_bounds__(256) void k4_gemm2(const void* __restrict__ adjraw,
        const int* __restrict__ modep,
        const u16* __restrict__ adjb, const u16* __restrict__ TsT,
        const float* __restrict__ dv, const float* __restrict__ dt_f,
        void* __restrict__ out, float* __restrict__ Pacc) {
    __shared__ __align__(16) u16 lA[8192];   // 16 KB: [0..4095] k-sub 0, [4096..8191] k-sub 1
    __shared__ __align__(16) u16 lB[8192];   // 16 KB
    int mode = *modep;
    const u16* A = mode ? adjb : (const u16*)adjraw;
    float* tgt = mode ? (float*)out : Pacc;
    int tid = threadIdx.x;
    int lane = tid & 63, wave = tid >> 6;
    int bm = blockIdx.x * 128, bn = blockIdx.y * 128;
    int kbase = blockIdx.z * KCHUNK;
    int wm = (wave & 1) * 64, wn = (wave >> 1) * 64;
    int quad = lane >> 4, l15 = lane & 15;

    const u16* Ab0 = A + (size_t)(bm + (tid >> 2)) * N_NODES + kbase + (tid & 3) * 8;
    const u16* Ab1 = A + (size_t)(bm + 64 + (tid >> 2)) * N_NODES + kbase + (tid & 3) * 8;
    const u16* Bb0 = TsT + (size_t)(bn + (tid >> 2)) * N_NODES + kbase + (tid & 3) * 8;
    const u16* Bb1 = TsT + (size_t)(bn + 64 + (tid >> 2)) * N_NODES + kbase + (tid & 3) * 8;
    u16* la00 = lA + tid * 8;        u16* la01 = lA + 2048 + tid * 8;   // k-sub 0
    u16* la10 = lA + 4096 + tid * 8; u16* la11 = lA + 6144 + tid * 8;   // k-sub 1
    u16* lb00 = lB + tid * 8;        u16* lb01 = lB + 2048 + tid * 8;
    u16* lb10 = lB + 4096 + tid * 8; u16* lb11 = lB + 6144 + tid * 8;

    f32x4 acc[4][4];
#pragma unroll
    for (int a = 0; a < 4; ++a)
#pragma unroll
        for (int b = 0; b < 4; ++b) acc[a][b] = (f32x4){0.f, 0.f, 0.f, 0.f};

    for (int k0 = 0; k0 < KCHUNK; k0 += 64) {
        gload16(Ab0 + k0, la00);
        gload16(Ab1 + k0, la01);
        gload16(Ab0 + k0 + 32, la10);
        gload16(Ab1 + k0 + 32, la11);
        gload16(Bb0 + k0, lb00);
        gload16(Bb1 + k0, lb01);
        gload16(Bb0 + k0 + 32, lb10);
        gload16(Bb1 + k0 + 32, lb11);
        __syncthreads();
#pragma unroll
        for (int kk = 0; kk < 2; ++kk) {
            const u16* baseA = lA + kk * 4096;
            const u16* baseB = lB + kk * 4096;
            bf16x8 af[4], bfv[4];
#pragma unroll
            for (int mt = 0; mt < 4; ++mt) af[mt] = *(const bf16x8*)&baseA[(wm + mt * 16 + l15) * 32 + quad * 8];
#pragma unroll
            for (int nt = 0; nt < 4; ++nt) bfv[nt] = *(const bf16x8*)&baseB[(wn + nt * 16 + l15) * 32 + quad * 8];
#pragma unroll
            for (int mt = 0; mt < 4; ++mt)
#pragma unroll
                for (int nt = 0; nt < 4; ++nt)
                    acc[mt][nt] = __builtin_amdgcn_mfma_f32_16x16x32_bf16(af[mt], bfv[nt], acc[mt][nt], 0, 0, 0);
        }
        __syncthreads();
    }

    float c1 = dt_f[0] * 4.f;  // dt / EPS
#pragma unroll
    for (int mt = 0; mt < 4; ++mt) {
        float inv[4];
#pragma unroll
        for (int r = 0; r < 4; ++r) inv[r] = c1 / dv[bm + wm + mt * 16 + quad * 4 + r];
#pragma unroll
        for (int nt = 0; nt < 4; ++nt) {
            int col = bn + wn + nt * 16 + l15;
#pragma unroll
            for (int r = 0; r < 4; ++r) {
                int row = bm + wm + mt * 16 + quad * 4 + r;
                atomicAdd(&tgt[(size_t)row * C_DIM + col], acc[mt][nt][r] * inv[r]);
            }
        }
    }
}

// ================= K5: bf16 finalize (no-op in f32 mode) =================
__global__ __launch_bounds__(256) void k5_fin(const int* __restrict__ modep,
                                              const float* __restrict__ Pacc,
                                              u16* __restrict__ out) {
    if (*modep) return;
    int idx = blockIdx.x * 256 + threadIdx.x;
    float4 v = ((const float4*)Pacc)[idx];
    ushort4 o; o.x = f2b(v.x); o.y = f2b(v.y); o.z = f2b(v.z); o.w = f2b(v.w);
    ((ushort4*)out)[idx] = o;
}

extern "C" void kernel_launch(void* const* d_in, const int* in_sizes, int n_in,
                              void* d_out, int out_size, void* d_ws, size_t ws_size,
                              hipStream_t stream) {
    const void* x   = d_in[0];
    const void* adj = d_in[1];
    const void* Wp  = d_in[2];
    const void* bp  = d_in[3];
    const void* Wp1 = d_in[4];
    const void* bp1 = d_in[5];
    const void* Wp2 = d_in[6];
    const void* bp2 = d_in[7];
    const void* Wf  = d_in[8];
    const void* bfc = d_in[9];
    const void* dtp = d_in[10];

    char* ws = (char*)d_ws;
    int*   modep  = (int*)(ws + OFF_MODE);
    float* dt_f   = (float*)(ws + OFF_DT);
    float* bias_f = (float*)(ws + OFF_BIAS);
    float* bp_f   = (float*)(ws + OFF_BP);
    float* bp1_f  = (float*)(ws + OFF_BP1);
    float* Wp2_f  = (float*)(ws + OFF_WP2);
    float* bp2_f  = (float*)(ws + OFF_BP2);
    float* q      = (float*)(ws + OFF_Q);
    float* s      = (float*)(ws + OFF_S);
    float* dv     = (float*)(ws + OFF_DV);
    u32*   WpP    = (u32*)(ws + OFF_WPP);
    u32*   Wp1P   = (u32*)(ws + OFF_WP1P);
    u16*   WfT    = (u16*)(ws + OFF_WFT);
    float* T      = (float*)(ws + OFF_T);
    u16*   TsT    = (u16*)(ws + OFF_TST);
    u16*   xb     = (u16*)(ws + OFF_XB);
    u16*   adjb   = (u16*)(ws + OFF_ADJB);
    float* Pacc   = (float*)(ws + OFF_ADJB);   // bf16 mode only: adjb unused there

    k1_prep<<<3463, 256, 0, stream>>>(adj, x, Wp, bp, Wp1, bp1, Wp2, bp2, Wf, bfc, dtp,
                                      modep, bp_f, bp1_f, Wp2_f, bp2_f, bias_f, dt_f,
                                      WpP, Wp1P, adjb, q, xb, WfT);
    k2_pi_gemm1<<<1024, 256, 0, stream>>>(x, modep, xb, WfT, WpP, Wp1P,
                                          bp_f, bp1_f, Wp2_f, bp2_f, bias_f, dt_f,
                                          q, s, T, d_out, Pacc);
    k3_mid<<<3072, 256, 0, stream>>>(adj, modep, adjb, s, T, dv, TsT);
    k4_gemm2<<<dim3(32, 4, SPLITS), 256, 0, stream>>>(adj, modep, adjb, TsT, dv, dt_f, d_out, Pacc);
    k5_fin<<<2048, 256, 0, stream>>>(modep, Pacc, (u16*)d_out);
}